// Round 7
// baseline (212.041 us; speedup 1.0000x reference)
//
#include <hip/hip_runtime.h>

// Chunked fast-weight linear attention, MI355X gfx950 — 3-kernel decomposition.
// K1 ttr_pt:     P_c = k_c^T v_c per (bh,chunk)            [1024 wgs]
// K2 ttr_prefix: W_c = exclusive prefix of P               [256 wgs]
// K3 ttr_out:    out = (mask(q k^T) v + q W_prev) / t      [4096 wgs]
// R6: K3 latency-bound at 2.1 wgs/CU -> raise concurrency: W straight
// global->regs (no w_lds), qW before B1, LDS 40KB -> 4 wgs/CU,
// launch_bounds(256,4), cvt_pkrtz packed f32->f16. Sibling remap kept.
// R6b: fix cvt_pkrtz return-type mismatch (__fp16 vs _Float16 vector).

typedef _Float16 f16;
typedef __attribute__((ext_vector_type(2))) _Float16 f16x2;
typedef __attribute__((ext_vector_type(4))) _Float16 f16x4;
typedef __attribute__((ext_vector_type(8))) _Float16 f16x8;
typedef __attribute__((ext_vector_type(16))) float f32x16;
typedef __attribute__((ext_vector_type(4))) float fv4;

#define MFMA32(a, b, c) __builtin_amdgcn_mfma_f32_32x32x16_f16((a), (b), (c), 0, 0, 0)

__device__ __forceinline__ f16x4 cvt4(fv4 x) {
  f16x2 lo = __builtin_bit_cast(f16x2, __builtin_amdgcn_cvt_pkrtz(x[0], x[1]));
  f16x2 hi = __builtin_bit_cast(f16x2, __builtin_amdgcn_cvt_pkrtz(x[2], x[3]));
  return __builtin_shufflevector(lo, hi, 0, 1, 2, 3);
}

// Byte offset into a row-major [*][128] f16 LDS tile; XOR key mixes row bits
// 0-2 and 3-5 so both 16-row and 32-row fragment reads spread evenly over
// banks. Consistent across all writers/readers -> layout-correct.
__device__ __forceinline__ int swzb(int row, int col) {
  int s = (row ^ (row >> 3)) & 7;
  return (row << 8) + ((col << 1) ^ (s << 4));
}

// 32x32x16 operand fragment: row = lane&31, k = kk*16 + 8*(lane>>5) + j.
// Same k-map on A and B operands -> contraction correct. One ds_read_b128.
__device__ __forceinline__ f16x8 frag32(const f16* lds, int row, int kk, int lane) {
  int c0 = (kk << 4) + ((lane >> 5) << 3);
  return *(const f16x8*)((const char*)lds + swzb(row, c0));
}

// 32x32 C/D row for acc reg r, lane-half g: row=(r&3)+8*(r>>2)+4*g  [m74/m101]
__device__ __forceinline__ int rowf(int r, int g) {
  return (r & 3) + ((r >> 2) << 3) + (g << 2);
}

// ---------------------------------------------------------------------------
// K1: P_c^T[v][f] = sum_s v[s][v] * k[s][f]
__global__ __launch_bounds__(512, 1)
void ttr_pt(const float* __restrict__ k, const float* __restrict__ v,
            f16* __restrict__ pt) {
  __shared__ f16 kT[128 * 128];
  __shared__ f16 vT[128 * 128];
  const int tid = threadIdx.x, lane = tid & 63, wave = tid >> 6;
  const int bh = blockIdx.x >> 5, c = blockIdx.x & 31;
  const float* kg = k + ((size_t)bh * 4096 + c * 128) * 128;
  const float* vg = v + ((size_t)bh * 4096 + c * 128) * 128;
  const int f0 = (tid & 31) << 2;
#pragma unroll
  for (int p = 0; p < 8; ++p) {
    int s = (p << 4) + (tid >> 5);
    fv4 xk = *(const fv4*)(kg + s * 128 + f0);
    fv4 xv = *(const fv4*)(vg + s * 128 + f0);
#pragma unroll
    for (int e = 0; e < 4; ++e) {
      *(f16*)((char*)kT + swzb(f0 + e, s)) = (f16)xk[e];
      *(f16*)((char*)vT + swzb(f0 + e, s)) = (f16)xv[e];
    }
  }
  __syncthreads();
  const int l31 = lane & 31, g = lane >> 5;
  const int mt = wave >> 1, nt0 = (wave & 1) << 1;
  f32x16 p0 = {0.f}, p1 = {0.f};
#pragma unroll
  for (int kk = 0; kk < 8; ++kk) {
    f16x8 a = frag32(vT, (mt << 5) + l31, kk, lane);
    p0 = MFMA32(a, frag32(kT, (nt0 << 5) + l31, kk, lane), p0);
    p1 = MFMA32(a, frag32(kT, ((nt0 + 1) << 5) + l31, kk, lane), p1);
  }
  f16* dst = pt + (size_t)blockIdx.x * 16384;
#pragma unroll
  for (int r = 0; r < 16; ++r) {
    int vr = (mt << 5) + rowf(r, g);
    dst[vr * 128 + (nt0 << 5) + l31] = (f16)p0[r];
    dst[vr * 128 + ((nt0 + 1) << 5) + l31] = (f16)p1[r];
  }
}

// ---------------------------------------------------------------------------
// K2: exclusive prefix over chunks; output in B-frag-permuted layout:
// per (bh,c), 16B unit u = (NT*8+kk)*64 + g*32 + laneC holds
// W[v = NT*32 + laneC][f = kk*16 + 8g .. +7]. Quarter NT is 8KB contiguous.
__global__ __launch_bounds__(256, 1)
void ttr_prefix(const f16* __restrict__ pt, f16* __restrict__ w) {
  __shared__ f16 xch[256 * 8];
  const int tid = threadIdx.x;
  const int bh = blockIdx.x >> 3, vs = blockIdx.x & 7;
  const int v0 = vs << 4;
  const int NT = v0 >> 5;
  const int vloc = tid >> 4, fblk = tid & 15;
  const size_t bhbase = (size_t)bh * 32 * 16384;
  const f16* src = pt + bhbase + (size_t)(v0 + vloc) * 128 + fblk * 8;
  const int kk = tid >> 5, gg = (tid >> 4) & 1, lc = tid & 15;
  f16* dstu = w + bhbase +
              (size_t)(((NT * 8 + kk) * 64) + gg * 32 + (v0 & 31) + lc) * 8;
  const int phi_w = vloc * 16 + (fblk ^ vloc);
  const int phi_r = lc * 16 + ((tid >> 4) ^ lc);
  float acc[8];
#pragma unroll
  for (int e = 0; e < 8; ++e) acc[e] = 0.f;
  for (int c = 0; c < 32; ++c) {
    f16x8 pcur = *(const f16x8*)(src + (size_t)c * 16384);
    f16x8 h;
#pragma unroll
    for (int e = 0; e < 8; ++e) h[e] = (f16)acc[e];
    *(f16x8*)(xch + phi_w * 8) = h;
    __syncthreads();
    f16x8 o = *(const f16x8*)(xch + phi_r * 8);
    *(f16x8*)(dstu + (size_t)c * 16384) = o;
    __syncthreads();
#pragma unroll
    for (int e = 0; e < 8; ++e) acc[e] += (float)pcur[e];
  }
}

// ---------------------------------------------------------------------------
// K3: wg = (bh, c, v-quarter). 4 waves; wave m owns out rows [32m,32m+32).
// q + W in regs; k/S + vT in LDS (40KB -> 4 wg/CU). 2 barriers.
__global__ __launch_bounds__(256, 4)
void ttr_out(const float* __restrict__ q, const float* __restrict__ k,
             const float* __restrict__ v, const f16* __restrict__ w,
             float* __restrict__ out) {
  __shared__ f16 s_lds[128 * 128];  // 32KB: k, then masked S (in place)
  __shared__ f16 vT[32 * 128];      // 8KB: v-quarter transposed
  const int tid = threadIdx.x, lane = tid & 63, wave = tid >> 6;
  const int l31 = lane & 31, g = lane >> 5;
  // sibling remap: the 4 wgs sharing (bh,c) are adjacent in dispatch and
  // congruent mod 8 -> same XCD, concurrent -> q/k/W L2-hot.
  const int widx = blockIdx.x & 31;
  const int gidx = ((blockIdx.x >> 5) << 3) + (widx & 7);  // (bh,c) in [0,1024)
  const int vq = widx >> 3;                                // v-quarter 0..3
  const int bh = gidx >> 5, c = gidx & 31;
  const float* qg = q + ((size_t)bh * 4096 + c * 128) * 128;
  const float* kg = k + ((size_t)bh * 4096 + c * 128) * 128;
  const float* vg = v + ((size_t)bh * 4096 + c * 128) * 128 + vq * 32;

  // W B-frags straight from global (K2's layout: unit kk*64+lane of the
  // vq quarter). All 4 waves read the same 8KB — L2-hot via siblings.
  const f16* wsrc = w + (size_t)gidx * 16384 + vq * 4096;
  f16x8 wf[8];
#pragma unroll
  for (int kk = 0; kk < 8; ++kk)
    wf[kk] = *(const f16x8*)(wsrc + (size_t)((kk << 6) + lane) * 8);

  // q A-frags: wave-private rows, col = kk*16 + 8g + j (frag32 k-map)
  f16x8 qf[8];
  {
    const float* qr = qg + ((wave << 5) + l31) * 128 + (g << 3);
#pragma unroll
    for (int kk = 0; kk < 8; ++kk) {
      f16x4 a = cvt4(*(const fv4*)(qr + (kk << 4)));
      f16x4 b = cvt4(*(const fv4*)(qr + (kk << 4) + 4));
      qf[kk] = __builtin_shufflevector(a, b, 0, 1, 2, 3, 4, 5, 6, 7);
    }
  }
  // stage k (f32 -> f16 packed, swizzled)
  {
    const int c0 = (tid & 31) << 2;
#pragma unroll
    for (int p = 0; p < 16; ++p) {
      int s = (p << 3) + (tid >> 5);
      *(f16x4*)((char*)s_lds + swzb(s, c0)) = cvt4(*(const fv4*)(kg + s * 128 + c0));
    }
  }
  // stage vT (v-quarter transposed; vT row = local v-col 0..31, col = s)
  {
    const int c0 = (tid & 7) << 2;
#pragma unroll
    for (int p = 0; p < 4; ++p) {
      int s = (p << 5) + (tid >> 3);
      fv4 xv = *(const fv4*)(vg + s * 128 + c0);
#pragma unroll
      for (int e = 0; e < 4; ++e)
        *(f16*)((char*)vT + swzb(c0 + e, s)) = (f16)xv[e];
    }
  }
  // qW from regs while staging stores drain (wf dies here -> low liveness)
  f32x16 o0 = {0.f};
#pragma unroll
  for (int kk = 0; kk < 8; ++kk) o0 = MFMA32(qf[kk], wf[kk], o0);
  __syncthreads();  // B1: k, vT staged

  // S tiles (wave, j<=wave). Static accum indices; wave-uniform guards.
  f32x16 s0 = {0.f}, s1 = {0.f}, s2 = {0.f}, s3 = {0.f};
#pragma unroll
  for (int kk = 0; kk < 8; ++kk) {
    f16x8 aq = qf[kk];
    s0 = MFMA32(aq, frag32(s_lds, l31, kk, lane), s0);
    if (wave >= 1) s1 = MFMA32(aq, frag32(s_lds, 32 + l31, kk, lane), s1);
    if (wave >= 2) s2 = MFMA32(aq, frag32(s_lds, 64 + l31, kk, lane), s2);
    if (wave >= 3) s3 = MFMA32(aq, frag32(s_lds, 96 + l31, kk, lane), s3);
  }
  __syncthreads();  // B2: all k reads done; s_lds rows become wave-private S

  // masked S -> s_lds rows [32*wave, 32*wave+32) (own rows only; no barrier
  // needed after — each wave re-reads only its own rows, lgkmcnt orders it)
#define STORE_S(ACC, J)                                                       \
  {                                                                           \
    const bool dg = ((J) == wave);                                            \
    _Pragma("unroll") for (int r = 0; r < 16; ++r) {                          \
      int rl = rowf(r, g);                                                    \
      float val = ACC[r];                                                     \
      if (dg && l31 > rl) val = 0.f;                                          \
      *(f16*)((char*)s_lds + swzb((wave << 5) + rl, ((J) << 5) + l31)) =      \
          (f16)val;                                                           \
    }                                                                         \
  }
  STORE_S(s0, 0);
  if (wave >= 1) STORE_S(s1, 1);
  if (wave >= 2) STORE_S(s2, 2);
  if (wave >= 3) STORE_S(s3, 3);

  // Sv over the causal k-range
  const int nkk = (wave + 1) << 1;
  for (int kk = 0; kk < nkk; ++kk)
    o0 = MFMA32(frag32(s_lds, (wave << 5) + l31, kk, lane),
                frag32(vT, l31, kk, lane), o0);

  float* og = out + (((size_t)bh * 4096) + c * 128 + (wave << 5)) * 128 + vq * 32;
#pragma unroll
  for (int r = 0; r < 16; ++r) {
    int rl = rowf(r, g);
    float tg = (float)(c * 128 + (wave << 5) + rl + 1);
    og[rl * 128 + l31] = o0[r] * __builtin_amdgcn_rcpf(tg);  // |rel|~1e-5 ok
  }
}

extern "C" void kernel_launch(void* const* d_in, const int* in_sizes, int n_in,
                              void* d_out, int out_size, void* d_ws, size_t ws_size,
                              hipStream_t stream) {
  const float* q = (const float*)d_in[0];
  const float* k = (const float*)d_in[1];
  const float* v = (const float*)d_in[2];
  float* o = (float*)d_out;
  f16* pt = (f16*)d_ws;
  f16* w = pt + (size_t)32 * 32 * 16384;
  ttr_pt<<<dim3(1024), dim3(512), 0, stream>>>(k, v, pt);
  ttr_prefix<<<dim3(256), dim3(256), 0, stream>>>(pt, w);
  ttr_out<<<dim3(4096), dim3(256), 0, stream>>>(q, k, v, w, o);
}

// Round 8
// 209.520 us; speedup vs baseline: 1.0120x; 1.0120x over previous
//
#include <hip/hip_runtime.h>

// Chunked fast-weight linear attention, MI355X gfx950 — 3-kernel decomposition.
// K1 ttr_pt:     P_c = k_c^T v_c per (bh,chunk)            [1024 wgs]
// K2 ttr_prefix: W_c = exclusive prefix of P               [256 wgs]
// K3 ttr_out:    out = (mask(q k^T) v + q W_prev) / t      [4096 wgs]
// R8: keep 4 wg/CU (R7's occupancy win) but fix the spill by liveness
// arithmetic: o0/qW moved AFTER the S phase, wf issued after B2.
// S-phase peak = qf(32)+s(64) = 96; tail peak = qf+wf+o0 = 80. Fits 128.

typedef _Float16 f16;
typedef __attribute__((ext_vector_type(2))) _Float16 f16x2;
typedef __attribute__((ext_vector_type(4))) _Float16 f16x4;
typedef __attribute__((ext_vector_type(8))) _Float16 f16x8;
typedef __attribute__((ext_vector_type(16))) float f32x16;
typedef __attribute__((ext_vector_type(4))) float fv4;

#define MFMA32(a, b, c) __builtin_amdgcn_mfma_f32_32x32x16_f16((a), (b), (c), 0, 0, 0)

__device__ __forceinline__ f16x4 cvt4(fv4 x) {
  f16x2 lo = __builtin_bit_cast(f16x2, __builtin_amdgcn_cvt_pkrtz(x[0], x[1]));
  f16x2 hi = __builtin_bit_cast(f16x2, __builtin_amdgcn_cvt_pkrtz(x[2], x[3]));
  return __builtin_shufflevector(lo, hi, 0, 1, 2, 3);
}

// Byte offset into a row-major [*][128] f16 LDS tile; XOR key mixes row bits
// 0-2 and 3-5 so both 16-row and 32-row fragment reads spread evenly over
// banks. Consistent across all writers/readers -> layout-correct.
__device__ __forceinline__ int swzb(int row, int col) {
  int s = (row ^ (row >> 3)) & 7;
  return (row << 8) + ((col << 1) ^ (s << 4));
}

// 32x32x16 operand fragment: row = lane&31, k = kk*16 + 8*(lane>>5) + j.
// Same k-map on A and B operands -> contraction correct. One ds_read_b128.
__device__ __forceinline__ f16x8 frag32(const f16* lds, int row, int kk, int lane) {
  int c0 = (kk << 4) + ((lane >> 5) << 3);
  return *(const f16x8*)((const char*)lds + swzb(row, c0));
}

// 32x32 C/D row for acc reg r, lane-half g: row=(r&3)+8*(r>>2)+4*g  [m74/m101]
__device__ __forceinline__ int rowf(int r, int g) {
  return (r & 3) + ((r >> 2) << 3) + (g << 2);
}

// ---------------------------------------------------------------------------
// K1: P_c^T[v][f] = sum_s v[s][v] * k[s][f]
__global__ __launch_bounds__(512, 1)
void ttr_pt(const float* __restrict__ k, const float* __restrict__ v,
            f16* __restrict__ pt) {
  __shared__ f16 kT[128 * 128];
  __shared__ f16 vT[128 * 128];
  const int tid = threadIdx.x, lane = tid & 63, wave = tid >> 6;
  const int bh = blockIdx.x >> 5, c = blockIdx.x & 31;
  const float* kg = k + ((size_t)bh * 4096 + c * 128) * 128;
  const float* vg = v + ((size_t)bh * 4096 + c * 128) * 128;
  const int f0 = (tid & 31) << 2;
#pragma unroll
  for (int p = 0; p < 8; ++p) {
    int s = (p << 4) + (tid >> 5);
    fv4 xk = *(const fv4*)(kg + s * 128 + f0);
    fv4 xv = *(const fv4*)(vg + s * 128 + f0);
#pragma unroll
    for (int e = 0; e < 4; ++e) {
      *(f16*)((char*)kT + swzb(f0 + e, s)) = (f16)xk[e];
      *(f16*)((char*)vT + swzb(f0 + e, s)) = (f16)xv[e];
    }
  }
  __syncthreads();
  const int l31 = lane & 31, g = lane >> 5;
  const int mt = wave >> 1, nt0 = (wave & 1) << 1;
  f32x16 p0 = {0.f}, p1 = {0.f};
#pragma unroll
  for (int kk = 0; kk < 8; ++kk) {
    f16x8 a = frag32(vT, (mt << 5) + l31, kk, lane);
    p0 = MFMA32(a, frag32(kT, (nt0 << 5) + l31, kk, lane), p0);
    p1 = MFMA32(a, frag32(kT, ((nt0 + 1) << 5) + l31, kk, lane), p1);
  }
  f16* dst = pt + (size_t)blockIdx.x * 16384;
#pragma unroll
  for (int r = 0; r < 16; ++r) {
    int vr = (mt << 5) + rowf(r, g);
    dst[vr * 128 + (nt0 << 5) + l31] = (f16)p0[r];
    dst[vr * 128 + ((nt0 + 1) << 5) + l31] = (f16)p1[r];
  }
}

// ---------------------------------------------------------------------------
// K2: exclusive prefix over chunks; output in B-frag-permuted layout:
// per (bh,c), 16B unit u = (NT*8+kk)*64 + g*32 + laneC holds
// W[v = NT*32 + laneC][f = kk*16 + 8g .. +7]. Quarter NT is 8KB contiguous.
__global__ __launch_bounds__(256, 1)
void ttr_prefix(const f16* __restrict__ pt, f16* __restrict__ w) {
  __shared__ f16 xch[256 * 8];
  const int tid = threadIdx.x;
  const int bh = blockIdx.x >> 3, vs = blockIdx.x & 7;
  const int v0 = vs << 4;
  const int NT = v0 >> 5;
  const int vloc = tid >> 4, fblk = tid & 15;
  const size_t bhbase = (size_t)bh * 32 * 16384;
  const f16* src = pt + bhbase + (size_t)(v0 + vloc) * 128 + fblk * 8;
  const int kk = tid >> 5, gg = (tid >> 4) & 1, lc = tid & 15;
  f16* dstu = w + bhbase +
              (size_t)(((NT * 8 + kk) * 64) + gg * 32 + (v0 & 31) + lc) * 8;
  const int phi_w = vloc * 16 + (fblk ^ vloc);
  const int phi_r = lc * 16 + ((tid >> 4) ^ lc);
  float acc[8];
#pragma unroll
  for (int e = 0; e < 8; ++e) acc[e] = 0.f;
  for (int c = 0; c < 32; ++c) {
    f16x8 pcur = *(const f16x8*)(src + (size_t)c * 16384);
    f16x8 h;
#pragma unroll
    for (int e = 0; e < 8; ++e) h[e] = (f16)acc[e];
    *(f16x8*)(xch + phi_w * 8) = h;
    __syncthreads();
    f16x8 o = *(const f16x8*)(xch + phi_r * 8);
    *(f16x8*)(dstu + (size_t)c * 16384) = o;
    __syncthreads();
#pragma unroll
    for (int e = 0; e < 8; ++e) acc[e] += (float)pcur[e];
  }
}

// ---------------------------------------------------------------------------
// K3: wg = (bh, c, v-quarter). 4 waves; wave m owns out rows [32m,32m+32).
// q in regs; k/S + vT in LDS (40KB -> 4 wg/CU). 2 barriers.
__global__ __launch_bounds__(256, 4)
void ttr_out(const float* __restrict__ q, const float* __restrict__ k,
             const float* __restrict__ v, const f16* __restrict__ w,
             float* __restrict__ out) {
  __shared__ f16 s_lds[128 * 128];  // 32KB: k, then masked S (in place)
  __shared__ f16 vT[32 * 128];      // 8KB: v-quarter transposed
  const int tid = threadIdx.x, lane = tid & 63, wave = tid >> 6;
  const int l31 = lane & 31, g = lane >> 5;
  // sibling remap: the 4 wgs sharing (bh,c) are adjacent in dispatch and
  // congruent mod 8 -> same XCD, concurrent -> q/k/W L2-hot.
  const int widx = blockIdx.x & 31;
  const int gidx = ((blockIdx.x >> 5) << 3) + (widx & 7);  // (bh,c) in [0,1024)
  const int vq = widx >> 3;                                // v-quarter 0..3
  const int bh = gidx >> 5, c = gidx & 31;
  const float* qg = q + ((size_t)bh * 4096 + c * 128) * 128;
  const float* kg = k + ((size_t)bh * 4096 + c * 128) * 128;
  const float* vg = v + ((size_t)bh * 4096 + c * 128) * 128 + vq * 32;

  // q A-frags: wave-private rows, col = kk*16 + 8g + j (frag32 k-map)
  f16x8 qf[8];
  {
    const float* qr = qg + ((wave << 5) + l31) * 128 + (g << 3);
#pragma unroll
    for (int kk = 0; kk < 8; ++kk) {
      f16x4 a = cvt4(*(const fv4*)(qr + (kk << 4)));
      f16x4 b = cvt4(*(const fv4*)(qr + (kk << 4) + 4));
      qf[kk] = __builtin_shufflevector(a, b, 0, 1, 2, 3, 4, 5, 6, 7);
    }
  }
  // stage k (f32 -> f16 packed, swizzled)
  {
    const int c0 = (tid & 31) << 2;
#pragma unroll
    for (int p = 0; p < 16; ++p) {
      int s = (p << 3) + (tid >> 5);
      *(f16x4*)((char*)s_lds + swzb(s, c0)) = cvt4(*(const fv4*)(kg + s * 128 + c0));
    }
  }
  // stage vT (v-quarter transposed; vT row = local v-col 0..31, col = s)
  {
    const int c0 = (tid & 7) << 2;
#pragma unroll
    for (int p = 0; p < 4; ++p) {
      int s = (p << 5) + (tid >> 3);
      fv4 xv = *(const fv4*)(vg + s * 128 + c0);
#pragma unroll
      for (int e = 0; e < 4; ++e)
        *(f16*)((char*)vT + swzb(c0 + e, s)) = (f16)xv[e];
    }
  }
  __syncthreads();  // B1: k, vT staged

  // S tiles (wave, j<=wave). Peak liveness here: qf(32) + s(<=64) = 96.
  f32x16 s0 = {0.f}, s1 = {0.f}, s2 = {0.f}, s3 = {0.f};
#pragma unroll
  for (int kk = 0; kk < 8; ++kk) {
    f16x8 aq = qf[kk];
    s0 = MFMA32(aq, frag32(s_lds, l31, kk, lane), s0);
    if (wave >= 1) s1 = MFMA32(aq, frag32(s_lds, 32 + l31, kk, lane), s1);
    if (wave >= 2) s2 = MFMA32(aq, frag32(s_lds, 64 + l31, kk, lane), s2);
    if (wave >= 3) s3 = MFMA32(aq, frag32(s_lds, 96 + l31, kk, lane), s3);
  }
  __syncthreads();  // B2: all k reads done; s_lds rows become wave-private S

  // W B-frags (K2's layout: unit kk*64+lane of the vq quarter, 8KB,
  // sibling-shared -> L2-hot). Issued here so latency hides under
  // S-stores + Sv; consumed only in the qW loop at the end.
  const f16* wsrc = w + (size_t)gidx * 16384 + vq * 4096;
  f16x8 wf[8];
#pragma unroll
  for (int kk = 0; kk < 8; ++kk)
    wf[kk] = *(const f16x8*)(wsrc + (size_t)((kk << 6) + lane) * 8);

  // masked S -> s_lds rows [32*wave, 32*wave+32) (own rows only; no barrier
  // needed after — each wave re-reads only its own rows, lgkmcnt orders it)
#define STORE_S(ACC, J)                                                       \
  {                                                                           \
    const bool dg = ((J) == wave);                                            \
    _Pragma("unroll") for (int r = 0; r < 16; ++r) {                          \
      int rl = rowf(r, g);                                                    \
      float val = ACC[r];                                                     \
      if (dg && l31 > rl) val = 0.f;                                          \
      *(f16*)((char*)s_lds + swzb((wave << 5) + rl, ((J) << 5) + l31)) =      \
          (f16)val;                                                           \
    }                                                                         \
  }
  STORE_S(s0, 0);
  if (wave >= 1) STORE_S(s1, 1);
  if (wave >= 2) STORE_S(s2, 2);
  if (wave >= 3) STORE_S(s3, 3);

  // Sv over the causal k-range (fresh accumulator; s-accs are dead now)
  f32x16 o0 = {0.f};
  const int nkk = (wave + 1) << 1;
  for (int kk = 0; kk < nkk; ++kk)
    o0 = MFMA32(frag32(s_lds, (wave << 5) + l31, kk, lane),
                frag32(vT, l31, kk, lane), o0);

  // qW from regs (wf arrives by now; tail peak: qf+wf+o0 = 80)
#pragma unroll
  for (int kk = 0; kk < 8; ++kk) o0 = MFMA32(qf[kk], wf[kk], o0);

  float* og = out + (((size_t)bh * 4096) + c * 128 + (wave << 5)) * 128 + vq * 32;
#pragma unroll
  for (int r = 0; r < 16; ++r) {
    int rl = rowf(r, g);
    float tg = (float)(c * 128 + (wave << 5) + rl + 1);
    og[rl * 128 + l31] = o0[r] * __builtin_amdgcn_rcpf(tg);  // |rel|~1e-5 ok
  }
}

extern "C" void kernel_launch(void* const* d_in, const int* in_sizes, int n_in,
                              void* d_out, int out_size, void* d_ws, size_t ws_size,
                              hipStream_t stream) {
  const float* q = (const float*)d_in[0];
  const float* k = (const float*)d_in[1];
  const float* v = (const float*)d_in[2];
  float* o = (float*)d_out;
  f16* pt = (f16*)d_ws;
  f16* w = pt + (size_t)32 * 32 * 16384;
  ttr_pt<<<dim3(1024), dim3(512), 0, stream>>>(k, v, pt);
  ttr_prefix<<<dim3(256), dim3(256), 0, stream>>>(pt, w);
  ttr_out<<<dim3(4096), dim3(256), 0, stream>>>(q, k, v, w, o);
}

// Round 9
// 114.731 us; speedup vs baseline: 1.8482x; 1.8262x over previous
//
#include <hip/hip_runtime.h>

// Chunked fast-weight linear attention, MI355X gfx950 — 3-kernel decomposition.
// K1 ttr_pt:     P_c = k_c^T v_c per (bh,chunk)            [1024 wgs]
// K2 ttr_prefix: W_c = exclusive prefix of P               [256 wgs]
// K3 ttr_out:    out = (mask(q k^T) v + q W_prev) / t      [4096 wgs]
// R9: K3 single-barrier rewrite. S computed TRANSPOSED (A=k, B=q) so each
// lane holds an S row; in-register cvt_pk + shfl_xor(32) transpose feeds Sv
// directly — no S store, no B2, one S-tile accumulator live (16 acc regs).
// qW first (wf dies early). Peak ~98 regs < 128 -> true 4 wg/CU, no spill.

typedef _Float16 f16;
typedef __attribute__((ext_vector_type(2))) _Float16 f16x2;
typedef __attribute__((ext_vector_type(4))) _Float16 f16x4;
typedef __attribute__((ext_vector_type(8))) _Float16 f16x8;
typedef __attribute__((ext_vector_type(16))) float f32x16;
typedef __attribute__((ext_vector_type(4))) float fv4;
typedef __attribute__((ext_vector_type(4))) int i32x4;

#define MFMA32(a, b, c) __builtin_amdgcn_mfma_f32_32x32x16_f16((a), (b), (c), 0, 0, 0)

__device__ __forceinline__ f16x4 cvt4(fv4 x) {
  f16x2 lo = __builtin_bit_cast(f16x2, __builtin_amdgcn_cvt_pkrtz(x[0], x[1]));
  f16x2 hi = __builtin_bit_cast(f16x2, __builtin_amdgcn_cvt_pkrtz(x[2], x[3]));
  return __builtin_shufflevector(lo, hi, 0, 1, 2, 3);
}

// Byte offset into a row-major [*][128] f16 LDS tile; XOR key mixes row bits
// 0-2 and 3-5 so 32-row fragment reads spread over banks. Consistent across
// all writers/readers -> layout-correct.
__device__ __forceinline__ int swzb(int row, int col) {
  int s = (row ^ (row >> 3)) & 7;
  return (row << 8) + ((col << 1) ^ (s << 4));
}

// 32x32x16 operand fragment: row = lane&31, k = kk*16 + 8*(lane>>5) + j.
// Same k-map on A and B operands -> contraction correct. One ds_read_b128.
__device__ __forceinline__ f16x8 frag32(const f16* lds, int row, int kk, int lane) {
  int c0 = (kk << 4) + ((lane >> 5) << 3);
  return *(const f16x8*)((const char*)lds + swzb(row, c0));
}

// 32x32 C/D row for acc reg r, lane-half g: row=(r&3)+8*(r>>2)+4*g  [m74/m101]
__device__ __forceinline__ int rowf(int r, int g) {
  return (r & 3) + ((r >> 2) << 3) + (g << 2);
}

// ---------------------------------------------------------------------------
// K1: P_c^T[v][f] = sum_s v[s][v] * k[s][f]
__global__ __launch_bounds__(512, 1)
void ttr_pt(const float* __restrict__ k, const float* __restrict__ v,
            f16* __restrict__ pt) {
  __shared__ f16 kT[128 * 128];
  __shared__ f16 vT[128 * 128];
  const int tid = threadIdx.x, lane = tid & 63, wave = tid >> 6;
  const int bh = blockIdx.x >> 5, c = blockIdx.x & 31;
  const float* kg = k + ((size_t)bh * 4096 + c * 128) * 128;
  const float* vg = v + ((size_t)bh * 4096 + c * 128) * 128;
  const int f0 = (tid & 31) << 2;
#pragma unroll
  for (int p = 0; p < 8; ++p) {
    int s = (p << 4) + (tid >> 5);
    fv4 xk = *(const fv4*)(kg + s * 128 + f0);
    fv4 xv = *(const fv4*)(vg + s * 128 + f0);
#pragma unroll
    for (int e = 0; e < 4; ++e) {
      *(f16*)((char*)kT + swzb(f0 + e, s)) = (f16)xk[e];
      *(f16*)((char*)vT + swzb(f0 + e, s)) = (f16)xv[e];
    }
  }
  __syncthreads();
  const int l31 = lane & 31, g = lane >> 5;
  const int mt = wave >> 1, nt0 = (wave & 1) << 1;
  f32x16 p0 = {0.f}, p1 = {0.f};
#pragma unroll
  for (int kk = 0; kk < 8; ++kk) {
    f16x8 a = frag32(vT, (mt << 5) + l31, kk, lane);
    p0 = MFMA32(a, frag32(kT, (nt0 << 5) + l31, kk, lane), p0);
    p1 = MFMA32(a, frag32(kT, ((nt0 + 1) << 5) + l31, kk, lane), p1);
  }
  f16* dst = pt + (size_t)blockIdx.x * 16384;
#pragma unroll
  for (int r = 0; r < 16; ++r) {
    int vr = (mt << 5) + rowf(r, g);
    dst[vr * 128 + (nt0 << 5) + l31] = (f16)p0[r];
    dst[vr * 128 + ((nt0 + 1) << 5) + l31] = (f16)p1[r];
  }
}

// ---------------------------------------------------------------------------
// K2: exclusive prefix over chunks; output in B-frag-permuted layout:
// per (bh,c), 16B unit u = (NT*8+kk)*64 + g*32 + laneC holds
// W[v = NT*32 + laneC][f = kk*16 + 8g .. +7]. Quarter NT is 8KB contiguous.
__global__ __launch_bounds__(256, 1)
void ttr_prefix(const f16* __restrict__ pt, f16* __restrict__ w) {
  __shared__ f16 xch[256 * 8];
  const int tid = threadIdx.x;
  const int bh = blockIdx.x >> 3, vs = blockIdx.x & 7;
  const int v0 = vs << 4;
  const int NT = v0 >> 5;
  const int vloc = tid >> 4, fblk = tid & 15;
  const size_t bhbase = (size_t)bh * 32 * 16384;
  const f16* src = pt + bhbase + (size_t)(v0 + vloc) * 128 + fblk * 8;
  const int kk = tid >> 5, gg = (tid >> 4) & 1, lc = tid & 15;
  f16* dstu = w + bhbase +
              (size_t)(((NT * 8 + kk) * 64) + gg * 32 + (v0 & 31) + lc) * 8;
  const int phi_w = vloc * 16 + (fblk ^ vloc);
  const int phi_r = lc * 16 + ((tid >> 4) ^ lc);
  float acc[8];
#pragma unroll
  for (int e = 0; e < 8; ++e) acc[e] = 0.f;
  for (int c = 0; c < 32; ++c) {
    f16x8 pcur = *(const f16x8*)(src + (size_t)c * 16384);
    f16x8 h;
#pragma unroll
    for (int e = 0; e < 8; ++e) h[e] = (f16)acc[e];
    *(f16x8*)(xch + phi_w * 8) = h;
    __syncthreads();
    f16x8 o = *(const f16x8*)(xch + phi_r * 8);
    *(f16x8*)(dstu + (size_t)c * 16384) = o;
    __syncthreads();
#pragma unroll
    for (int e = 0; e < 8; ++e) acc[e] += (float)pcur[e];
  }
}

// ---------------------------------------------------------------------------
// K3: wg = (bh, c, v-quarter). 4 waves; wave m owns out rows [32m,32m+32).
// Single barrier. k + vT in LDS (40KB -> 4 wg/CU); S never touches LDS.
__global__ __launch_bounds__(256, 4)
void ttr_out(const float* __restrict__ q, const float* __restrict__ k,
             const float* __restrict__ v, const f16* __restrict__ w,
             float* __restrict__ out) {
  __shared__ f16 k_lds[128 * 128];  // 32KB (read-only after B1)
  __shared__ f16 vT[32 * 128];      // 8KB: v-quarter transposed
  const int tid = threadIdx.x, lane = tid & 63, wave = tid >> 6;
  const int l31 = lane & 31, g = lane >> 5;
  // sibling remap: the 4 wgs sharing (bh,c) are adjacent in dispatch and
  // congruent mod 8 -> same XCD, concurrent -> q/k/W L2-hot.
  const int widx = blockIdx.x & 31;
  const int gidx = ((blockIdx.x >> 5) << 3) + (widx & 7);  // (bh,c) in [0,1024)
  const int vq = widx >> 3;                                // v-quarter 0..3
  const int bh = gidx >> 5, c = gidx & 31;
  const float* qg = q + ((size_t)bh * 4096 + c * 128) * 128;
  const float* kg = k + ((size_t)bh * 4096 + c * 128) * 128;
  const float* vg = v + ((size_t)bh * 4096 + c * 128) * 128 + vq * 32;

  // W B-frags (K2 layout: unit kk*64+lane of the vq quarter; 8KB,
  // sibling-shared -> L2-hot). Issued FIRST; consumed right after B1.
  const f16* wsrc = w + (size_t)gidx * 16384 + vq * 4096;
  f16x8 wf[8];
#pragma unroll
  for (int kk = 0; kk < 8; ++kk)
    wf[kk] = *(const f16x8*)(wsrc + (size_t)((kk << 6) + lane) * 8);

  // q A/B-frags: wave-private rows, k-map = kk*16 + 8g + j (frag32 map)
  f16x8 qf[8];
  {
    const float* qr = qg + ((wave << 5) + l31) * 128 + (g << 3);
#pragma unroll
    for (int kk = 0; kk < 8; ++kk) {
      f16x4 a = cvt4(*(const fv4*)(qr + (kk << 4)));
      f16x4 b = cvt4(*(const fv4*)(qr + (kk << 4) + 4));
      qf[kk] = __builtin_shufflevector(a, b, 0, 1, 2, 3, 4, 5, 6, 7);
    }
  }
  // stage k (f32 -> f16 packed, swizzled)
  {
    const int c0 = (tid & 31) << 2;
#pragma unroll
    for (int p = 0; p < 16; ++p) {
      int s = (p << 3) + (tid >> 5);
      *(f16x4*)((char*)k_lds + swzb(s, c0)) = cvt4(*(const fv4*)(kg + s * 128 + c0));
    }
  }
  // stage vT (v-quarter transposed; vT row = local v-col 0..31, col = s)
  {
    const int c0 = (tid & 7) << 2;
#pragma unroll
    for (int p = 0; p < 4; ++p) {
      int s = (p << 5) + (tid >> 3);
      fv4 xv = *(const fv4*)(vg + s * 128 + c0);
#pragma unroll
      for (int e = 0; e < 4; ++e)
        *(f16*)((char*)vT + swzb(c0 + e, s)) = (f16)xv[e];
    }
  }
  __syncthreads();  // B1 — the ONLY barrier

  // qW first: wf dies here; o0 accumulates everything from now on.
  f32x16 o0 = {0.f};
#pragma unroll
  for (int kk = 0; kk < 8; ++kk) o0 = MFMA32(qf[kk], wf[kk], o0);

  // Causal tiles j = 0..wave. S^T = MFMA(A=k block j, B=qf):
  // lane l31 holds S[i=l31][j_local = rowf(r,g)] — one acc tile live.
  for (int j = 0; j <= wave; ++j) {
    f32x16 sa = {0.f};
#pragma unroll
    for (int kk = 0; kk < 8; ++kk)
      sa = MFMA32(frag32(k_lds, (j << 5) + l31, kk, lane), qf[kk], sa);
    if (j == wave) {  // diagonal: keep j_local <= i (inclusive causal)
#pragma unroll
      for (int r = 0; r < 16; ++r)
        if (rowf(r, g) > l31) sa[r] = 0.f;
    }
    // pack rows to f16 pairs: wds[t] = (j_local 2t, 2t+1) of this lane's row
    int wds[8];
#pragma unroll
    for (int t = 0; t < 8; ++t)
      wds[t] = __builtin_bit_cast(
          int, __builtin_amdgcn_cvt_pkrtz(sa[2 * t], sa[2 * t + 1]));
    // g-half exchange (lane <-> lane^32): assemble Sv A-frags
    int rA = __shfl_xor(g ? wds[0] : wds[2], 32, 64);
    int rB = __shfl_xor(g ? wds[1] : wds[3], 32, 64);
    int rC = __shfl_xor(g ? wds[4] : wds[6], 32, 64);
    int rD = __shfl_xor(g ? wds[5] : wds[7], 32, 64);
    i32x4 P0 = {g ? rA : wds[0], g ? rB : wds[1],
                g ? wds[2] : rA, g ? wds[3] : rB};
    i32x4 P1 = {g ? rC : wds[4], g ? rD : wds[5],
                g ? wds[6] : rC, g ? wds[7] : rD};
    f16x8 pa0 = __builtin_bit_cast(f16x8, P0);
    f16x8 pa1 = __builtin_bit_cast(f16x8, P1);
    // Sv: out rows i (lane) x v-cols (vT rows), k-range of tile j
    o0 = MFMA32(pa0, frag32(vT, l31, (j << 1), lane), o0);
    o0 = MFMA32(pa1, frag32(vT, l31, (j << 1) + 1, lane), o0);
  }

  float* og = out + (((size_t)bh * 4096) + c * 128 + (wave << 5)) * 128 + vq * 32;
#pragma unroll
  for (int r = 0; r < 16; ++r) {
    int rl = rowf(r, g);
    float tg = (float)(c * 128 + (wave << 5) + rl + 1);
    og[rl * 128 + l31] = o0[r] * __builtin_amdgcn_rcpf(tg);  // |rel|~1e-5 ok
  }
}

extern "C" void kernel_launch(void* const* d_in, const int* in_sizes, int n_in,
                              void* d_out, int out_size, void* d_ws, size_t ws_size,
                              hipStream_t stream) {
  const float* q = (const float*)d_in[0];
  const float* k = (const float*)d_in[1];
  const float* v = (const float*)d_in[2];
  float* o = (float*)d_out;
  f16* pt = (f16*)d_ws;
  f16* w = pt + (size_t)32 * 32 * 16384;
  ttr_pt<<<dim3(1024), dim3(512), 0, stream>>>(k, v, pt);
  ttr_prefix<<<dim3(256), dim3(256), 0, stream>>>(pt, w);
  ttr_out<<<dim3(4096), dim3(256), 0, stream>>>(q, k, v, w, o);
}

// Round 10
// 110.448 us; speedup vs baseline: 1.9198x; 1.0388x over previous
//
#include <hip/hip_runtime.h>

// Chunked fast-weight linear attention, MI355X gfx950 — 3-kernel decomposition.
// K1 ttr_pt:     P_c = k_c^T v_c per (bh,chunk)            [1024 wgs]
// K2 ttr_prefix: W_c = exclusive prefix of P               [256 wgs]
// K3 ttr_out:    out = (mask(q k^T) v + q W_prev) / t      [4096 wgs]
// R10: R9's single-barrier K3 (S^T via A=k,B=q; in-register cvt_pk +
// shfl_xor(32) transpose; no S in LDS) at launch_bounds(256,3).
// R7/R8/R9 proved the 128-reg class always spills (VGPR pinned 64, scratch
// in WRITE_SIZE); 170 regs @ 3 wg/CU is the no-spill operating point.

typedef _Float16 f16;
typedef __attribute__((ext_vector_type(2))) _Float16 f16x2;
typedef __attribute__((ext_vector_type(4))) _Float16 f16x4;
typedef __attribute__((ext_vector_type(8))) _Float16 f16x8;
typedef __attribute__((ext_vector_type(16))) float f32x16;
typedef __attribute__((ext_vector_type(4))) float fv4;
typedef __attribute__((ext_vector_type(4))) int i32x4;

#define MFMA32(a, b, c) __builtin_amdgcn_mfma_f32_32x32x16_f16((a), (b), (c), 0, 0, 0)

__device__ __forceinline__ f16x4 cvt4(fv4 x) {
  f16x2 lo = __builtin_bit_cast(f16x2, __builtin_amdgcn_cvt_pkrtz(x[0], x[1]));
  f16x2 hi = __builtin_bit_cast(f16x2, __builtin_amdgcn_cvt_pkrtz(x[2], x[3]));
  return __builtin_shufflevector(lo, hi, 0, 1, 2, 3);
}

// Byte offset into a row-major [*][128] f16 LDS tile; XOR key mixes row bits
// 0-2 and 3-5 so 32-row fragment reads spread over banks. Consistent across
// all writers/readers -> layout-correct.
__device__ __forceinline__ int swzb(int row, int col) {
  int s = (row ^ (row >> 3)) & 7;
  return (row << 8) + ((col << 1) ^ (s << 4));
}

// 32x32x16 operand fragment: row = lane&31, k = kk*16 + 8*(lane>>5) + j.
// Same k-map on A and B operands -> contraction correct. One ds_read_b128.
__device__ __forceinline__ f16x8 frag32(const f16* lds, int row, int kk, int lane) {
  int c0 = (kk << 4) + ((lane >> 5) << 3);
  return *(const f16x8*)((const char*)lds + swzb(row, c0));
}

// 32x32 C/D row for acc reg r, lane-half g: row=(r&3)+8*(r>>2)+4*g  [m74/m101]
__device__ __forceinline__ int rowf(int r, int g) {
  return (r & 3) + ((r >> 2) << 3) + (g << 2);
}

// ---------------------------------------------------------------------------
// K1: P_c^T[v][f] = sum_s v[s][v] * k[s][f]
__global__ __launch_bounds__(512, 1)
void ttr_pt(const float* __restrict__ k, const float* __restrict__ v,
            f16* __restrict__ pt) {
  __shared__ f16 kT[128 * 128];
  __shared__ f16 vT[128 * 128];
  const int tid = threadIdx.x, lane = tid & 63, wave = tid >> 6;
  const int bh = blockIdx.x >> 5, c = blockIdx.x & 31;
  const float* kg = k + ((size_t)bh * 4096 + c * 128) * 128;
  const float* vg = v + ((size_t)bh * 4096 + c * 128) * 128;
  const int f0 = (tid & 31) << 2;
#pragma unroll
  for (int p = 0; p < 8; ++p) {
    int s = (p << 4) + (tid >> 5);
    fv4 xk = *(const fv4*)(kg + s * 128 + f0);
    fv4 xv = *(const fv4*)(vg + s * 128 + f0);
#pragma unroll
    for (int e = 0; e < 4; ++e) {
      *(f16*)((char*)kT + swzb(f0 + e, s)) = (f16)xk[e];
      *(f16*)((char*)vT + swzb(f0 + e, s)) = (f16)xv[e];
    }
  }
  __syncthreads();
  const int l31 = lane & 31, g = lane >> 5;
  const int mt = wave >> 1, nt0 = (wave & 1) << 1;
  f32x16 p0 = {0.f}, p1 = {0.f};
#pragma unroll
  for (int kk = 0; kk < 8; ++kk) {
    f16x8 a = frag32(vT, (mt << 5) + l31, kk, lane);
    p0 = MFMA32(a, frag32(kT, (nt0 << 5) + l31, kk, lane), p0);
    p1 = MFMA32(a, frag32(kT, ((nt0 + 1) << 5) + l31, kk, lane), p1);
  }
  f16* dst = pt + (size_t)blockIdx.x * 16384;
#pragma unroll
  for (int r = 0; r < 16; ++r) {
    int vr = (mt << 5) + rowf(r, g);
    dst[vr * 128 + (nt0 << 5) + l31] = (f16)p0[r];
    dst[vr * 128 + ((nt0 + 1) << 5) + l31] = (f16)p1[r];
  }
}

// ---------------------------------------------------------------------------
// K2: exclusive prefix over chunks; output in B-frag-permuted layout:
// per (bh,c), 16B unit u = (NT*8+kk)*64 + g*32 + laneC holds
// W[v = NT*32 + laneC][f = kk*16 + 8g .. +7]. Quarter NT is 8KB contiguous.
__global__ __launch_bounds__(256, 1)
void ttr_prefix(const f16* __restrict__ pt, f16* __restrict__ w) {
  __shared__ f16 xch[256 * 8];
  const int tid = threadIdx.x;
  const int bh = blockIdx.x >> 3, vs = blockIdx.x & 7;
  const int v0 = vs << 4;
  const int NT = v0 >> 5;
  const int vloc = tid >> 4, fblk = tid & 15;
  const size_t bhbase = (size_t)bh * 32 * 16384;
  const f16* src = pt + bhbase + (size_t)(v0 + vloc) * 128 + fblk * 8;
  const int kk = tid >> 5, gg = (tid >> 4) & 1, lc = tid & 15;
  f16* dstu = w + bhbase +
              (size_t)(((NT * 8 + kk) * 64) + gg * 32 + (v0 & 31) + lc) * 8;
  const int phi_w = vloc * 16 + (fblk ^ vloc);
  const int phi_r = lc * 16 + ((tid >> 4) ^ lc);
  float acc[8];
#pragma unroll
  for (int e = 0; e < 8; ++e) acc[e] = 0.f;
  for (int c = 0; c < 32; ++c) {
    f16x8 pcur = *(const f16x8*)(src + (size_t)c * 16384);
    f16x8 h;
#pragma unroll
    for (int e = 0; e < 8; ++e) h[e] = (f16)acc[e];
    *(f16x8*)(xch + phi_w * 8) = h;
    __syncthreads();
    f16x8 o = *(const f16x8*)(xch + phi_r * 8);
    *(f16x8*)(dstu + (size_t)c * 16384) = o;
    __syncthreads();
#pragma unroll
    for (int e = 0; e < 8; ++e) acc[e] += (float)pcur[e];
  }
}

// ---------------------------------------------------------------------------
// K3: wg = (bh, c, v-quarter). 4 waves; wave m owns out rows [32m,32m+32).
// Single barrier. k + vT in LDS (40KB); S never touches LDS. 3 wg/CU.
__global__ __launch_bounds__(256, 3)
void ttr_out(const float* __restrict__ q, const float* __restrict__ k,
             const float* __restrict__ v, const f16* __restrict__ w,
             float* __restrict__ out) {
  __shared__ f16 k_lds[128 * 128];  // 32KB (read-only after B1)
  __shared__ f16 vT[32 * 128];      // 8KB: v-quarter transposed
  const int tid = threadIdx.x, lane = tid & 63, wave = tid >> 6;
  const int l31 = lane & 31, g = lane >> 5;
  // sibling remap: the 4 wgs sharing (bh,c) are adjacent in dispatch and
  // congruent mod 8 -> same XCD, concurrent -> q/k/W L2-hot.
  const int widx = blockIdx.x & 31;
  const int gidx = ((blockIdx.x >> 5) << 3) + (widx & 7);  // (bh,c) in [0,1024)
  const int vq = widx >> 3;                                // v-quarter 0..3
  const int bh = gidx >> 5, c = gidx & 31;
  const float* qg = q + ((size_t)bh * 4096 + c * 128) * 128;
  const float* kg = k + ((size_t)bh * 4096 + c * 128) * 128;
  const float* vg = v + ((size_t)bh * 4096 + c * 128) * 128 + vq * 32;

  // W B-frags (K2 layout: unit kk*64+lane of the vq quarter; 8KB,
  // sibling-shared -> L2-hot). Issued FIRST; consumed right after B1.
  const f16* wsrc = w + (size_t)gidx * 16384 + vq * 4096;
  f16x8 wf[8];
#pragma unroll
  for (int kk = 0; kk < 8; ++kk)
    wf[kk] = *(const f16x8*)(wsrc + (size_t)((kk << 6) + lane) * 8);

  // q A/B-frags: wave-private rows, k-map = kk*16 + 8g + j (frag32 map)
  f16x8 qf[8];
  {
    const float* qr = qg + ((wave << 5) + l31) * 128 + (g << 3);
#pragma unroll
    for (int kk = 0; kk < 8; ++kk) {
      f16x4 a = cvt4(*(const fv4*)(qr + (kk << 4)));
      f16x4 b = cvt4(*(const fv4*)(qr + (kk << 4) + 4));
      qf[kk] = __builtin_shufflevector(a, b, 0, 1, 2, 3, 4, 5, 6, 7);
    }
  }
  // stage k (f32 -> f16 packed, swizzled)
  {
    const int c0 = (tid & 31) << 2;
#pragma unroll
    for (int p = 0; p < 16; ++p) {
      int s = (p << 3) + (tid >> 5);
      *(f16x4*)((char*)k_lds + swzb(s, c0)) = cvt4(*(const fv4*)(kg + s * 128 + c0));
    }
  }
  // stage vT (v-quarter transposed; vT row = local v-col 0..31, col = s)
  {
    const int c0 = (tid & 7) << 2;
#pragma unroll
    for (int p = 0; p < 4; ++p) {
      int s = (p << 5) + (tid >> 3);
      fv4 xv = *(const fv4*)(vg + s * 128 + c0);
#pragma unroll
      for (int e = 0; e < 4; ++e)
        *(f16*)((char*)vT + swzb(c0 + e, s)) = (f16)xv[e];
    }
  }
  __syncthreads();  // B1 — the ONLY barrier

  // qW first: wf dies here; o0 accumulates everything from now on.
  f32x16 o0 = {0.f};
#pragma unroll
  for (int kk = 0; kk < 8; ++kk) o0 = MFMA32(qf[kk], wf[kk], o0);

  // Causal tiles j = 0..wave. S^T = MFMA(A=k block j, B=qf):
  // lane l31 holds S[i=l31][j_local = rowf(r,g)] — one acc tile live.
  for (int j = 0; j <= wave; ++j) {
    f32x16 sa = {0.f};
#pragma unroll
    for (int kk = 0; kk < 8; ++kk)
      sa = MFMA32(frag32(k_lds, (j << 5) + l31, kk, lane), qf[kk], sa);
    if (j == wave) {  // diagonal: keep j_local <= i (inclusive causal)
#pragma unroll
      for (int r = 0; r < 16; ++r)
        if (rowf(r, g) > l31) sa[r] = 0.f;
    }
    // pack rows to f16 pairs: wds[t] = (j_local 2t, 2t+1) of this lane's row
    int wds[8];
#pragma unroll
    for (int t = 0; t < 8; ++t)
      wds[t] = __builtin_bit_cast(
          int, __builtin_amdgcn_cvt_pkrtz(sa[2 * t], sa[2 * t + 1]));
    // g-half exchange (lane <-> lane^32): assemble Sv A-frags
    int rA = __shfl_xor(g ? wds[0] : wds[2], 32, 64);
    int rB = __shfl_xor(g ? wds[1] : wds[3], 32, 64);
    int rC = __shfl_xor(g ? wds[4] : wds[6], 32, 64);
    int rD = __shfl_xor(g ? wds[5] : wds[7], 32, 64);
    i32x4 P0 = {g ? rA : wds[0], g ? rB : wds[1],
                g ? wds[2] : rA, g ? wds[3] : rB};
    i32x4 P1 = {g ? rC : wds[4], g ? rD : wds[5],
                g ? wds[6] : rC, g ? wds[7] : rD};
    f16x8 pa0 = __builtin_bit_cast(f16x8, P0);
    f16x8 pa1 = __builtin_bit_cast(f16x8, P1);
    // Sv: out rows i (lane) x v-cols (vT rows), k-range of tile j
    o0 = MFMA32(pa0, frag32(vT, l31, (j << 1), lane), o0);
    o0 = MFMA32(pa1, frag32(vT, l31, (j << 1) + 1, lane), o0);
  }

  float* og = out + (((size_t)bh * 4096) + c * 128 + (wave << 5)) * 128 + vq * 32;
#pragma unroll
  for (int r = 0; r < 16; ++r) {
    int rl = rowf(r, g);
    float tg = (float)(c * 128 + (wave << 5) + rl + 1);
    og[rl * 128 + l31] = o0[r] * __builtin_amdgcn_rcpf(tg);  // |rel|~1e-5 ok
  }
}

extern "C" void kernel_launch(void* const* d_in, const int* in_sizes, int n_in,
                              void* d_out, int out_size, void* d_ws, size_t ws_size,
                              hipStream_t stream) {
  const float* q = (const float*)d_in[0];
  const float* k = (const float*)d_in[1];
  const float* v = (const float*)d_in[2];
  float* o = (float*)d_out;
  f16* pt = (f16*)d_ws;
  f16* w = pt + (size_t)32 * 32 * 16384;
  ttr_pt<<<dim3(1024), dim3(512), 0, stream>>>(k, v, pt);
  ttr_prefix<<<dim3(256), dim3(256), 0, stream>>>(pt, w);
  ttr_out<<<dim3(4096), dim3(256), 0, stream>>>(q, k, v, w, o);
}

// Round 11
// 96.066 us; speedup vs baseline: 2.2072x; 1.1497x over previous
//
#include <hip/hip_runtime.h>

// Chunked fast-weight linear attention, MI355X gfx950 — 3-kernel decomposition.
// K1 ttr_pt:     P_c = k_c^T v_c per (bh,chunk)            [1024 wgs]
// K2 ttr_prefix: W_c = exclusive prefix of P               [256 wgs]
// K3 ttr_out:    out = (mask(q k^T) v + q W_prev) / t      [2048 wgs]
// R11: K3 v-quarter -> v-HALF (64 cols/wg). Evidence: R3/R5/R10 all ~75us
// regardless of structure/occupancy -> per-wg latency-bound; the lever is
// compute density + replication. S-replication 4x->2x, q/k re-reads halve,
// 46 MFMAs/wave. Same single-barrier no-spill skeleton at (256,3), 48KB LDS.

typedef _Float16 f16;
typedef __attribute__((ext_vector_type(2))) _Float16 f16x2;
typedef __attribute__((ext_vector_type(4))) _Float16 f16x4;
typedef __attribute__((ext_vector_type(8))) _Float16 f16x8;
typedef __attribute__((ext_vector_type(16))) float f32x16;
typedef __attribute__((ext_vector_type(4))) float fv4;
typedef __attribute__((ext_vector_type(4))) int i32x4;

#define MFMA32(a, b, c) __builtin_amdgcn_mfma_f32_32x32x16_f16((a), (b), (c), 0, 0, 0)

__device__ __forceinline__ f16x4 cvt4(fv4 x) {
  f16x2 lo = __builtin_bit_cast(f16x2, __builtin_amdgcn_cvt_pkrtz(x[0], x[1]));
  f16x2 hi = __builtin_bit_cast(f16x2, __builtin_amdgcn_cvt_pkrtz(x[2], x[3]));
  return __builtin_shufflevector(lo, hi, 0, 1, 2, 3);
}

// Byte offset into a row-major [*][128] f16 LDS tile; XOR key mixes row bits
// 0-2 and 3-5 so 32-row fragment reads spread over banks. Consistent across
// all writers/readers -> layout-correct.
__device__ __forceinline__ int swzb(int row, int col) {
  int s = (row ^ (row >> 3)) & 7;
  return (row << 8) + ((col << 1) ^ (s << 4));
}

// 32x32x16 operand fragment: row = lane&31, k = kk*16 + 8*(lane>>5) + j.
// Same k-map on A and B operands -> contraction correct. One ds_read_b128.
__device__ __forceinline__ f16x8 frag32(const f16* lds, int row, int kk, int lane) {
  int c0 = (kk << 4) + ((lane >> 5) << 3);
  return *(const f16x8*)((const char*)lds + swzb(row, c0));
}

// 32x32 C/D row for acc reg r, lane-half g: row=(r&3)+8*(r>>2)+4*g  [m74/m101]
__device__ __forceinline__ int rowf(int r, int g) {
  return (r & 3) + ((r >> 2) << 3) + (g << 2);
}

// ---------------------------------------------------------------------------
// K1: P_c^T[v][f] = sum_s v[s][v] * k[s][f]
__global__ __launch_bounds__(512, 1)
void ttr_pt(const float* __restrict__ k, const float* __restrict__ v,
            f16* __restrict__ pt) {
  __shared__ f16 kT[128 * 128];
  __shared__ f16 vT[128 * 128];
  const int tid = threadIdx.x, lane = tid & 63, wave = tid >> 6;
  const int bh = blockIdx.x >> 5, c = blockIdx.x & 31;
  const float* kg = k + ((size_t)bh * 4096 + c * 128) * 128;
  const float* vg = v + ((size_t)bh * 4096 + c * 128) * 128;
  const int f0 = (tid & 31) << 2;
#pragma unroll
  for (int p = 0; p < 8; ++p) {
    int s = (p << 4) + (tid >> 5);
    fv4 xk = *(const fv4*)(kg + s * 128 + f0);
    fv4 xv = *(const fv4*)(vg + s * 128 + f0);
#pragma unroll
    for (int e = 0; e < 4; ++e) {
      *(f16*)((char*)kT + swzb(f0 + e, s)) = (f16)xk[e];
      *(f16*)((char*)vT + swzb(f0 + e, s)) = (f16)xv[e];
    }
  }
  __syncthreads();
  const int l31 = lane & 31, g = lane >> 5;
  const int mt = wave >> 1, nt0 = (wave & 1) << 1;
  f32x16 p0 = {0.f}, p1 = {0.f};
#pragma unroll
  for (int kk = 0; kk < 8; ++kk) {
    f16x8 a = frag32(vT, (mt << 5) + l31, kk, lane);
    p0 = MFMA32(a, frag32(kT, (nt0 << 5) + l31, kk, lane), p0);
    p1 = MFMA32(a, frag32(kT, ((nt0 + 1) << 5) + l31, kk, lane), p1);
  }
  f16* dst = pt + (size_t)blockIdx.x * 16384;
#pragma unroll
  for (int r = 0; r < 16; ++r) {
    int vr = (mt << 5) + rowf(r, g);
    dst[vr * 128 + (nt0 << 5) + l31] = (f16)p0[r];
    dst[vr * 128 + ((nt0 + 1) << 5) + l31] = (f16)p1[r];
  }
}

// ---------------------------------------------------------------------------
// K2: exclusive prefix over chunks; output in B-frag-permuted layout:
// per (bh,c), 16B unit u = (NT*8+kk)*64 + g*32 + laneC holds
// W[v = NT*32 + laneC][f = kk*16 + 8g .. +7]. Quarter NT is 8KB contiguous.
__global__ __launch_bounds__(256, 1)
void ttr_prefix(const f16* __restrict__ pt, f16* __restrict__ w) {
  __shared__ f16 xch[256 * 8];
  const int tid = threadIdx.x;
  const int bh = blockIdx.x >> 3, vs = blockIdx.x & 7;
  const int v0 = vs << 4;
  const int NT = v0 >> 5;
  const int vloc = tid >> 4, fblk = tid & 15;
  const size_t bhbase = (size_t)bh * 32 * 16384;
  const f16* src = pt + bhbase + (size_t)(v0 + vloc) * 128 + fblk * 8;
  const int kk = tid >> 5, gg = (tid >> 4) & 1, lc = tid & 15;
  f16* dstu = w + bhbase +
              (size_t)(((NT * 8 + kk) * 64) + gg * 32 + (v0 & 31) + lc) * 8;
  const int phi_w = vloc * 16 + (fblk ^ vloc);
  const int phi_r = lc * 16 + ((tid >> 4) ^ lc);
  float acc[8];
#pragma unroll
  for (int e = 0; e < 8; ++e) acc[e] = 0.f;
  for (int c = 0; c < 32; ++c) {
    f16x8 pcur = *(const f16x8*)(src + (size_t)c * 16384);
    f16x8 h;
#pragma unroll
    for (int e = 0; e < 8; ++e) h[e] = (f16)acc[e];
    *(f16x8*)(xch + phi_w * 8) = h;
    __syncthreads();
    f16x8 o = *(const f16x8*)(xch + phi_r * 8);
    *(f16x8*)(dstu + (size_t)c * 16384) = o;
    __syncthreads();
#pragma unroll
    for (int e = 0; e < 8; ++e) acc[e] += (float)pcur[e];
  }
}

// ---------------------------------------------------------------------------
// K3: wg = (bh, c, v-half). 4 waves; wave m owns out rows [32m,32m+32) x 64 v.
// Single barrier. k (32KB) + vT (16KB) in LDS; S never touches LDS. 3 wg/CU.
__global__ __launch_bounds__(256, 3)
void ttr_out(const float* __restrict__ q, const float* __restrict__ k,
             const float* __restrict__ v, const f16* __restrict__ w,
             float* __restrict__ out) {
  __shared__ f16 k_lds[128 * 128];  // 32KB (read-only after B1)
  __shared__ f16 vT[64 * 128];      // 16KB: v-half transposed
  const int tid = threadIdx.x, lane = tid & 63, wave = tid >> 6;
  const int l31 = lane & 31, g = lane >> 5;
  // sibling remap: the 2 wgs sharing (bh,c) are in the same 16-window and
  // differ by 8 in blockIdx -> same XCD, concurrent -> q/k L2-hot.
  const int widx = blockIdx.x & 15;
  const int gidx = ((blockIdx.x >> 4) << 3) + (widx & 7);  // (bh,c) in [0,1024)
  const int vh = widx >> 3;                                // v-half 0..1
  const int bh = gidx >> 5, c = gidx & 31;
  const float* qg = q + ((size_t)bh * 4096 + c * 128) * 128;
  const float* kg = k + ((size_t)bh * 4096 + c * 128) * 128;
  const float* vg = v + ((size_t)bh * 4096 + c * 128) * 128 + vh * 64;

  // W B-frags (K2 layout): two 32-col quarters NT = 2*vh, 2*vh+1.
  // 16KB sibling-shared -> L2-hot. Issued FIRST; die right after B1 (qW).
  const f16* wsrc = w + (size_t)gidx * 16384 + (size_t)(vh * 2) * 4096;
  f16x8 wf0[8], wf1[8];
#pragma unroll
  for (int kk = 0; kk < 8; ++kk) {
    wf0[kk] = *(const f16x8*)(wsrc + (size_t)((kk << 6) + lane) * 8);
    wf1[kk] = *(const f16x8*)(wsrc + (size_t)(4096 + ((kk << 6) + lane) * 8));
  }

  // q A/B-frags: wave-private rows, k-map = kk*16 + 8g + j (frag32 map)
  f16x8 qf[8];
  {
    const float* qr = qg + ((wave << 5) + l31) * 128 + (g << 3);
#pragma unroll
    for (int kk = 0; kk < 8; ++kk) {
      f16x4 a = cvt4(*(const fv4*)(qr + (kk << 4)));
      f16x4 b = cvt4(*(const fv4*)(qr + (kk << 4) + 4));
      qf[kk] = __builtin_shufflevector(a, b, 0, 1, 2, 3, 4, 5, 6, 7);
    }
  }
  // stage k (f32 -> f16 packed, swizzled)
  {
    const int c0 = (tid & 31) << 2;
#pragma unroll
    for (int p = 0; p < 16; ++p) {
      int s = (p << 3) + (tid >> 5);
      *(f16x4*)((char*)k_lds + swzb(s, c0)) = cvt4(*(const fv4*)(kg + s * 128 + c0));
    }
  }
  // stage vT (v-half transposed; vT row = local v-col 0..63, col = s)
  {
    const int c0 = (tid & 15) << 2;
#pragma unroll
    for (int p = 0; p < 8; ++p) {
      int s = (p << 4) + (tid >> 4);
      fv4 xv = *(const fv4*)(vg + s * 128 + c0);
#pragma unroll
      for (int e = 0; e < 4; ++e)
        *(f16*)((char*)vT + swzb(c0 + e, s)) = (f16)xv[e];
    }
  }
  __syncthreads();  // B1 — the ONLY barrier

  // qW first: wf0/wf1 die here; o0/o1 accumulate everything from now on.
  f32x16 o0 = {0.f}, o1 = {0.f};
#pragma unroll
  for (int kk = 0; kk < 8; ++kk) {
    o0 = MFMA32(qf[kk], wf0[kk], o0);
    o1 = MFMA32(qf[kk], wf1[kk], o1);
  }

  // Causal tiles j = 0..wave. S^T = MFMA(A=k block j, B=qf):
  // lane l31 holds S[i=l31][j_local = rowf(r,g)] — one acc tile live.
  for (int j = 0; j <= wave; ++j) {
    f32x16 sa = {0.f};
#pragma unroll
    for (int kk = 0; kk < 8; ++kk)
      sa = MFMA32(frag32(k_lds, (j << 5) + l31, kk, lane), qf[kk], sa);
    if (j == wave) {  // diagonal: keep j_local <= i (inclusive causal)
#pragma unroll
      for (int r = 0; r < 16; ++r)
        if (rowf(r, g) > l31) sa[r] = 0.f;
    }
    // pack rows to f16 pairs: wds[t] = (j_local 2t, 2t+1) of this lane's row
    int wds[8];
#pragma unroll
    for (int t = 0; t < 8; ++t)
      wds[t] = __builtin_bit_cast(
          int, __builtin_amdgcn_cvt_pkrtz(sa[2 * t], sa[2 * t + 1]));
    // g-half exchange (lane <-> lane^32): assemble Sv A-frags
    int rA = __shfl_xor(g ? wds[0] : wds[2], 32, 64);
    int rB = __shfl_xor(g ? wds[1] : wds[3], 32, 64);
    int rC = __shfl_xor(g ? wds[4] : wds[6], 32, 64);
    int rD = __shfl_xor(g ? wds[5] : wds[7], 32, 64);
    i32x4 P0 = {g ? rA : wds[0], g ? rB : wds[1],
                g ? wds[2] : rA, g ? wds[3] : rB};
    i32x4 P1 = {g ? rC : wds[4], g ? rD : wds[5],
                g ? wds[6] : rC, g ? wds[7] : rD};
    f16x8 pa0 = __builtin_bit_cast(f16x8, P0);
    f16x8 pa1 = __builtin_bit_cast(f16x8, P1);
    // Sv: out rows i (lane) x 64 v-cols (two vT row-tiles), k-range tile j
    o0 = MFMA32(pa0, frag32(vT, l31, (j << 1), lane), o0);
    o0 = MFMA32(pa1, frag32(vT, l31, (j << 1) + 1, lane), o0);
    o1 = MFMA32(pa0, frag32(vT, 32 + l31, (j << 1), lane), o1);
    o1 = MFMA32(pa1, frag32(vT, 32 + l31, (j << 1) + 1, lane), o1);
  }

  float* og = out + (((size_t)bh * 4096) + c * 128 + (wave << 5)) * 128 + vh * 64;
#pragma unroll
  for (int r = 0; r < 16; ++r) {
    int rl = rowf(r, g);
    float tg = (float)(c * 128 + (wave << 5) + rl + 1);
    float rcp = __builtin_amdgcn_rcpf(tg);  // |rel|~1e-5 ok
    og[rl * 128 + l31] = o0[r] * rcp;
    og[rl * 128 + 32 + l31] = o1[r] * rcp;
  }
}

extern "C" void kernel_launch(void* const* d_in, const int* in_sizes, int n_in,
                              void* d_out, int out_size, void* d_ws, size_t ws_size,
                              hipStream_t stream) {
  const float* q = (const float*)d_in[0];
  const float* k = (const float*)d_in[1];
  const float* v = (const float*)d_in[2];
  float* o = (float*)d_out;
  f16* pt = (f16*)d_ws;
  f16* w = pt + (size_t)32 * 32 * 16384;
  ttr_pt<<<dim3(1024), dim3(512), 0, stream>>>(k, v, pt);
  ttr_prefix<<<dim3(256), dim3(256), 0, stream>>>(pt, w);
  ttr_out<<<dim3(2048), dim3(256), 0, stream>>>(q, k, v, w, o);
}

// Round 12
// 95.972 us; speedup vs baseline: 2.2094x; 1.0010x over previous
//
#include <hip/hip_runtime.h>

// Chunked fast-weight linear attention, MI355X gfx950 — 3-kernel decomposition.
// K1 ttr_pt:     P_c = k_c^T v_c per (bh,chunk)            [1024 wgs]
// K2 ttr_prefix: W_c = exclusive prefix of P               [256 wgs]
// K3 ttr_out:    out = (mask(q k^T) v + q W_prev) / t      [1024 wgs]
// R12: K3 v-half -> v-FULL (one wg per (bh,c)). S-replication 1x, q/k read
// once, 104 MFMAs/wave. LDS 64KB -> 2 wg/CU; launch_bounds(256,2) gives a
// 256-reg budget so all 4 W quarters live in regs (peak ~224, spill-free by
// construction). Single barrier kept from R10/R11.

typedef _Float16 f16;
typedef __attribute__((ext_vector_type(2))) _Float16 f16x2;
typedef __attribute__((ext_vector_type(4))) _Float16 f16x4;
typedef __attribute__((ext_vector_type(8))) _Float16 f16x8;
typedef __attribute__((ext_vector_type(16))) float f32x16;
typedef __attribute__((ext_vector_type(4))) float fv4;
typedef __attribute__((ext_vector_type(4))) int i32x4;

#define MFMA32(a, b, c) __builtin_amdgcn_mfma_f32_32x32x16_f16((a), (b), (c), 0, 0, 0)

__device__ __forceinline__ f16x4 cvt4(fv4 x) {
  f16x2 lo = __builtin_bit_cast(f16x2, __builtin_amdgcn_cvt_pkrtz(x[0], x[1]));
  f16x2 hi = __builtin_bit_cast(f16x2, __builtin_amdgcn_cvt_pkrtz(x[2], x[3]));
  return __builtin_shufflevector(lo, hi, 0, 1, 2, 3);
}

// Byte offset into a row-major [*][128] f16 LDS tile; XOR key mixes row bits
// 0-2 and 3-5 so 32-row fragment reads spread over banks. Consistent across
// all writers/readers -> layout-correct.
__device__ __forceinline__ int swzb(int row, int col) {
  int s = (row ^ (row >> 3)) & 7;
  return (row << 8) + ((col << 1) ^ (s << 4));
}

// 32x32x16 operand fragment: row = lane&31, k = kk*16 + 8*(lane>>5) + j.
// Same k-map on A and B operands -> contraction correct. One ds_read_b128.
__device__ __forceinline__ f16x8 frag32(const f16* lds, int row, int kk, int lane) {
  int c0 = (kk << 4) + ((lane >> 5) << 3);
  return *(const f16x8*)((const char*)lds + swzb(row, c0));
}

// 32x32 C/D row for acc reg r, lane-half g: row=(r&3)+8*(r>>2)+4*g  [m74/m101]
__device__ __forceinline__ int rowf(int r, int g) {
  return (r & 3) + ((r >> 2) << 3) + (g << 2);
}

// ---------------------------------------------------------------------------
// K1: P_c^T[v][f] = sum_s v[s][v] * k[s][f]
__global__ __launch_bounds__(512, 1)
void ttr_pt(const float* __restrict__ k, const float* __restrict__ v,
            f16* __restrict__ pt) {
  __shared__ f16 kT[128 * 128];
  __shared__ f16 vT[128 * 128];
  const int tid = threadIdx.x, lane = tid & 63, wave = tid >> 6;
  const int bh = blockIdx.x >> 5, c = blockIdx.x & 31;
  const float* kg = k + ((size_t)bh * 4096 + c * 128) * 128;
  const float* vg = v + ((size_t)bh * 4096 + c * 128) * 128;
  const int f0 = (tid & 31) << 2;
#pragma unroll
  for (int p = 0; p < 8; ++p) {
    int s = (p << 4) + (tid >> 5);
    fv4 xk = *(const fv4*)(kg + s * 128 + f0);
    fv4 xv = *(const fv4*)(vg + s * 128 + f0);
#pragma unroll
    for (int e = 0; e < 4; ++e) {
      *(f16*)((char*)kT + swzb(f0 + e, s)) = (f16)xk[e];
      *(f16*)((char*)vT + swzb(f0 + e, s)) = (f16)xv[e];
    }
  }
  __syncthreads();
  const int l31 = lane & 31, g = lane >> 5;
  const int mt = wave >> 1, nt0 = (wave & 1) << 1;
  f32x16 p0 = {0.f}, p1 = {0.f};
#pragma unroll
  for (int kk = 0; kk < 8; ++kk) {
    f16x8 a = frag32(vT, (mt << 5) + l31, kk, lane);
    p0 = MFMA32(a, frag32(kT, (nt0 << 5) + l31, kk, lane), p0);
    p1 = MFMA32(a, frag32(kT, ((nt0 + 1) << 5) + l31, kk, lane), p1);
  }
  f16* dst = pt + (size_t)blockIdx.x * 16384;
#pragma unroll
  for (int r = 0; r < 16; ++r) {
    int vr = (mt << 5) + rowf(r, g);
    dst[vr * 128 + (nt0 << 5) + l31] = (f16)p0[r];
    dst[vr * 128 + ((nt0 + 1) << 5) + l31] = (f16)p1[r];
  }
}

// ---------------------------------------------------------------------------
// K2: exclusive prefix over chunks; output in B-frag-permuted layout:
// per (bh,c), 16B unit u = (NT*8+kk)*64 + g*32 + laneC holds
// W[v = NT*32 + laneC][f = kk*16 + 8g .. +7]. Quarter NT is 8KB contiguous.
__global__ __launch_bounds__(256, 1)
void ttr_prefix(const f16* __restrict__ pt, f16* __restrict__ w) {
  __shared__ f16 xch[256 * 8];
  const int tid = threadIdx.x;
  const int bh = blockIdx.x >> 3, vs = blockIdx.x & 7;
  const int v0 = vs << 4;
  const int NT = v0 >> 5;
  const int vloc = tid >> 4, fblk = tid & 15;
  const size_t bhbase = (size_t)bh * 32 * 16384;
  const f16* src = pt + bhbase + (size_t)(v0 + vloc) * 128 + fblk * 8;
  const int kk = tid >> 5, gg = (tid >> 4) & 1, lc = tid & 15;
  f16* dstu = w + bhbase +
              (size_t)(((NT * 8 + kk) * 64) + gg * 32 + (v0 & 31) + lc) * 8;
  const int phi_w = vloc * 16 + (fblk ^ vloc);
  const int phi_r = lc * 16 + ((tid >> 4) ^ lc);
  float acc[8];
#pragma unroll
  for (int e = 0; e < 8; ++e) acc[e] = 0.f;
  for (int c = 0; c < 32; ++c) {
    f16x8 pcur = *(const f16x8*)(src + (size_t)c * 16384);
    f16x8 h;
#pragma unroll
    for (int e = 0; e < 8; ++e) h[e] = (f16)acc[e];
    *(f16x8*)(xch + phi_w * 8) = h;
    __syncthreads();
    f16x8 o = *(const f16x8*)(xch + phi_r * 8);
    *(f16x8*)(dstu + (size_t)c * 16384) = o;
    __syncthreads();
#pragma unroll
    for (int e = 0; e < 8; ++e) acc[e] += (float)pcur[e];
  }
}

// ---------------------------------------------------------------------------
// K3: wg = (bh, c). 4 waves; wave m owns out rows [32m,32m+32) x all 128 v.
// Single barrier. k (32KB) + vT (32KB) in LDS; W in regs (4 quarters).
__global__ __launch_bounds__(256, 2)
void ttr_out(const float* __restrict__ q, const float* __restrict__ k,
             const float* __restrict__ v, const f16* __restrict__ w,
             float* __restrict__ out) {
  __shared__ f16 k_lds[128 * 128];  // 32KB (read-only after B1)
  __shared__ f16 vT[128 * 128];     // 32KB: v transposed
  const int tid = threadIdx.x, lane = tid & 63, wave = tid >> 6;
  const int l31 = lane & 31, g = lane >> 5;
  const int gidx = blockIdx.x;  // (bh,c) in [0,1024)
  const int bh = gidx >> 5, c = gidx & 31;
  const float* qg = q + ((size_t)bh * 4096 + c * 128) * 128;
  const float* kg = k + ((size_t)bh * 4096 + c * 128) * 128;
  const float* vg = v + ((size_t)bh * 4096 + c * 128) * 128;

  // All 4 W quarters -> regs (128 VGPRs). Issued FIRST (deepest latency);
  // consumed right after B1, then dead for the rest of the kernel.
  const f16* wsrc = w + (size_t)gidx * 16384;
  f16x8 wf0[8], wf1[8], wf2[8], wf3[8];
#pragma unroll
  for (int kk = 0; kk < 8; ++kk) {
    int u = ((kk << 6) + lane) * 8;
    wf0[kk] = *(const f16x8*)(wsrc + u);
    wf1[kk] = *(const f16x8*)(wsrc + 4096 + u);
    wf2[kk] = *(const f16x8*)(wsrc + 8192 + u);
    wf3[kk] = *(const f16x8*)(wsrc + 12288 + u);
  }

  // q A/B-frags: wave-private rows, k-map = kk*16 + 8g + j (frag32 map)
  f16x8 qf[8];
  {
    const float* qr = qg + ((wave << 5) + l31) * 128 + (g << 3);
#pragma unroll
    for (int kk = 0; kk < 8; ++kk) {
      f16x4 a = cvt4(*(const fv4*)(qr + (kk << 4)));
      f16x4 b = cvt4(*(const fv4*)(qr + (kk << 4) + 4));
      qf[kk] = __builtin_shufflevector(a, b, 0, 1, 2, 3, 4, 5, 6, 7);
    }
  }
  // stage k (f32 -> f16 packed, swizzled)
  {
    const int c0 = (tid & 31) << 2;
#pragma unroll
    for (int p = 0; p < 16; ++p) {
      int s = (p << 3) + (tid >> 5);
      *(f16x4*)((char*)k_lds + swzb(s, c0)) = cvt4(*(const fv4*)(kg + s * 128 + c0));
    }
  }
  // stage vT (all 128 v-cols transposed; vT row = v-col, col = s)
  {
    const int c0 = (tid & 31) << 2;
#pragma unroll
    for (int p = 0; p < 16; ++p) {
      int s = (p << 3) + (tid >> 5);
      fv4 xv = *(const fv4*)(vg + s * 128 + c0);
#pragma unroll
      for (int e = 0; e < 4; ++e)
        *(f16*)((char*)vT + swzb(c0 + e, s)) = (f16)xv[e];
    }
  }
  __syncthreads();  // B1 — the ONLY barrier

  // qW: all four quarters; wf dies here, o0-3 accumulate from now on.
  f32x16 o0 = {0.f}, o1 = {0.f}, o2 = {0.f}, o3 = {0.f};
#pragma unroll
  for (int kk = 0; kk < 8; ++kk) {
    o0 = MFMA32(qf[kk], wf0[kk], o0);
    o1 = MFMA32(qf[kk], wf1[kk], o1);
    o2 = MFMA32(qf[kk], wf2[kk], o2);
    o3 = MFMA32(qf[kk], wf3[kk], o3);
  }

  // Causal tiles j = 0..wave. S^T = MFMA(A=k block j, B=qf):
  // lane l31 holds S[i=l31][j_local = rowf(r,g)] — one acc tile live.
  for (int j = 0; j <= wave; ++j) {
    f32x16 sa = {0.f};
#pragma unroll
    for (int kk = 0; kk < 8; ++kk)
      sa = MFMA32(frag32(k_lds, (j << 5) + l31, kk, lane), qf[kk], sa);
    if (j == wave) {  // diagonal: keep j_local <= i (inclusive causal)
#pragma unroll
      for (int r = 0; r < 16; ++r)
        if (rowf(r, g) > l31) sa[r] = 0.f;
    }
    // pack rows to f16 pairs: wds[t] = (j_local 2t, 2t+1) of this lane's row
    int wds[8];
#pragma unroll
    for (int t = 0; t < 8; ++t)
      wds[t] = __builtin_bit_cast(
          int, __builtin_amdgcn_cvt_pkrtz(sa[2 * t], sa[2 * t + 1]));
    // g-half exchange (lane <-> lane^32): assemble Sv A-frags
    int rA = __shfl_xor(g ? wds[0] : wds[2], 32, 64);
    int rB = __shfl_xor(g ? wds[1] : wds[3], 32, 64);
    int rC = __shfl_xor(g ? wds[4] : wds[6], 32, 64);
    int rD = __shfl_xor(g ? wds[5] : wds[7], 32, 64);
    i32x4 P0 = {g ? rA : wds[0], g ? rB : wds[1],
                g ? wds[2] : rA, g ? wds[3] : rB};
    i32x4 P1 = {g ? rC : wds[4], g ? rD : wds[5],
                g ? wds[6] : rC, g ? wds[7] : rD};
    f16x8 pa0 = __builtin_bit_cast(f16x8, P0);
    f16x8 pa1 = __builtin_bit_cast(f16x8, P1);
    // Sv: out rows i (lane) x 128 v-cols (four vT row-tiles), k-range tile j
    o0 = MFMA32(pa0, frag32(vT, l31, (j << 1), lane), o0);
    o0 = MFMA32(pa1, frag32(vT, l31, (j << 1) + 1, lane), o0);
    o1 = MFMA32(pa0, frag32(vT, 32 + l31, (j << 1), lane), o1);
    o1 = MFMA32(pa1, frag32(vT, 32 + l31, (j << 1) + 1, lane), o1);
    o2 = MFMA32(pa0, frag32(vT, 64 + l31, (j << 1), lane), o2);
    o2 = MFMA32(pa1, frag32(vT, 64 + l31, (j << 1) + 1, lane), o2);
    o3 = MFMA32(pa0, frag32(vT, 96 + l31, (j << 1), lane), o3);
    o3 = MFMA32(pa1, frag32(vT, 96 + l31, (j << 1) + 1, lane), o3);
  }

  float* og = out + (((size_t)bh * 4096) + c * 128 + (wave << 5)) * 128;
#pragma unroll
  for (int r = 0; r < 16; ++r) {
    int rl = rowf(r, g);
    float tg = (float)(c * 128 + (wave << 5) + rl + 1);
    float rcp = __builtin_amdgcn_rcpf(tg);  // |rel|~1e-5 ok
    og[rl * 128 + l31] = o0[r] * rcp;
    og[rl * 128 + 32 + l31] = o1[r] * rcp;
    og[rl * 128 + 64 + l31] = o2[r] * rcp;
    og[rl * 128 + 96 + l31] = o3[r] * rcp;
  }
}

extern "C" void kernel_launch(void* const* d_in, const int* in_sizes, int n_in,
                              void* d_out, int out_size, void* d_ws, size_t ws_size,
                              hipStream_t stream) {
  const float* q = (const float*)d_in[0];
  const float* k = (const float*)d_in[1];
  const float* v = (const float*)d_in[2];
  float* o = (float*)d_out;
  f16* pt = (f16*)d_ws;
  f16* w = pt + (size_t)32 * 32 * 16384;
  ttr_pt<<<dim3(1024), dim3(512), 0, stream>>>(k, v, pt);
  ttr_prefix<<<dim3(256), dim3(256), 0, stream>>>(pt, w);
  ttr_out<<<dim3(1024), dim3(256), 0, stream>>>(q, k, v, w, o);
}